// Round 2
// baseline (687.302 us; speedup 1.0000x reference)
//
#include <hip/hip_runtime.h>
#include <hip/hip_fp16.h>
#include <type_traits>

#define NDIM 256
#define NHEAD 4
#define DHEAD 64
#define NSNAP 8192
#define PER 32
#define NPAP 200000
#define SLOPE 0.01f

using half8   = __attribute__((ext_vector_type(8))) _Float16;
using floatx4 = __attribute__((ext_vector_type(4))) float;

__device__ __forceinline__ float leaky(float x) { return x >= 0.f ? x : SLOPE * x; }

__device__ __forceinline__ unsigned pack2(float a, float b) {
    __half2 h = __floats2half2_rn(a, b);
    return *reinterpret_cast<unsigned*>(&h);
}

// C[M,256] = A[rows][256] @ W[256,256]^T + bias
// If aidx != nullptr, A-row for output row m is aidx[e0 + m] (gather-GEMM).
// AT = float or __half (A dtype); OT = __half or float (output dtype)
template <typename AT, typename OT>
__global__ __launch_bounds__(256) void gemm_nt(const AT* __restrict__ A,
                                               const float* __restrict__ W,
                                               const float* __restrict__ bias,
                                               OT* __restrict__ Cout, int M,
                                               const int* __restrict__ aidx, int e0) {
    constexpr int LDA = 40;  // halfs; +8 pad, rows stay 8B-aligned
    __shared__ _Float16 Asl[128 * LDA];
    __shared__ _Float16 Wsl[128 * LDA];

    const int m0 = blockIdx.x * 128;
    const int n0 = blockIdx.y * 128;
    const int tid = threadIdx.x;
    const int lane = tid & 63;
    const int wave = tid >> 6;
    const int wm = (wave & 1) * 64;
    const int wn = (wave >> 1) * 64;
    const int l15 = lane & 15;
    const int quad = lane >> 4;

    // per-thread A-row resolution for the 4 staging rows this thread touches
    floatx4 acc[4][4];
#pragma unroll
    for (int i = 0; i < 4; i++)
#pragma unroll
        for (int j = 0; j < 4; j++) acc[i][j] = (floatx4)0.f;

    for (int k0 = 0; k0 < 256; k0 += 32) {
        __syncthreads();
#pragma unroll
        for (int it = 0; it < 4; ++it) {
            const int idx = tid + it * 256;  // 1024 groups of 4 elements
            const int row = idx >> 3;
            const int c4 = idx & 7;
            long gm = (long)m0 + row;
            if (gm >= M) gm = M - 1;  // clamp; stores are guarded
            const long arow = aidx ? (long)aidx[e0 + gm] : gm;
            if constexpr (std::is_same_v<AT, float>) {
                const float4 v = *(const float4*)(A + arow * 256 + k0 + c4 * 4);
                *(uint2*)(&Asl[row * LDA + c4 * 4]) = make_uint2(pack2(v.x, v.y), pack2(v.z, v.w));
            } else {
                const uint2 v = *(const uint2*)(A + arow * 256 + k0 + c4 * 4);
                *(uint2*)(&Asl[row * LDA + c4 * 4]) = v;
            }
            const float4 w = *(const float4*)(W + (long)(n0 + row) * 256 + k0 + c4 * 4);
            *(uint2*)(&Wsl[row * LDA + c4 * 4]) = make_uint2(pack2(w.x, w.y), pack2(w.z, w.w));
        }
        __syncthreads();

        half8 af[4], bf[4];
#pragma unroll
        for (int i = 0; i < 4; i++)
            af[i] = *reinterpret_cast<const half8*>(&Asl[(wm + i * 16 + l15) * LDA + quad * 8]);
#pragma unroll
        for (int j = 0; j < 4; j++)
            bf[j] = *reinterpret_cast<const half8*>(&Wsl[(wn + j * 16 + l15) * LDA + quad * 8]);
#pragma unroll
        for (int i = 0; i < 4; i++)
#pragma unroll
            for (int j = 0; j < 4; j++)
                acc[i][j] = __builtin_amdgcn_mfma_f32_16x16x32_f16(af[i], bf[j], acc[i][j], 0, 0, 0);
    }

    // epilogue: C/D layout col = lane&15, row = quad*4 + r
#pragma unroll
    for (int j = 0; j < 4; j++) {
        const int gcol = n0 + wn + j * 16 + l15;
        const float bv = bias[gcol];
#pragma unroll
        for (int i = 0; i < 4; i++) {
            const int rbase = m0 + wm + i * 16 + quad * 4;
#pragma unroll
            for (int r = 0; r < 4; r++) {
                const int grow = rbase + r;
                if (grow < M) {
                    const float v = acc[i][j][r] + bv;
                    if constexpr (std::is_same_v<OT, __half>)
                        Cout[(long)grow * 256 + gcol] = __float2half(v);
                    else
                        Cout[(long)grow * 256 + gcol] = v;
                }
            }
        }
    }
}

// one block (256 threads) per snapshot; feat rows for this chunk are CONTIGUOUS
__global__ __launch_bounds__(256) void attn_kernel(
    const __half* __restrict__ feat, const float* __restrict__ F,
    const float* __restrict__ emb_cite, const float* __restrict__ emb_ref,
    const float* __restrict__ emb_target, const float* __restrict__ snap_emb,
    const float* __restrict__ attn, const float* __restrict__ attn_t,
    const int* __restrict__ types, const int* __restrict__ is_cite,
    const int* __restrict__ sel, int s0, __half* __restrict__ sum_out) {
    const int s = s0 + blockIdx.x;
    const int tid = threadIdx.x;
    const int lane = tid & 63;
    const int wave = tid >> 6;

    __shared__ _Float16 Tl[32 * 256];
    __shared__ int ic_l[32];
    __shared__ float et_l[2][4];
    __shared__ float e_l[32][4];
    __shared__ float a_l[32][4];

    if (tid < 32) {
        const int p = sel[(long)s * 32 + tid];
        ic_l[tid] = is_cite[p];
    }

    // stage this snapshot's 32 feat rows (contiguous 16 KB) into LDS
    const long fbase = (long)blockIdx.x * 32 * 256;
#pragma unroll
    for (int it = 0; it < 4; ++it) {
        const int idx = tid + it * 256;
        *(uint4*)(&Tl[idx * 8]) = *(const uint4*)(feat + fbase + idx * 8);
    }

    const float f = F[(long)s * 256 + tid];
    const float av = attn[tid];
    const float atv = attn_t[tid];
    const int st = types[s];
    const float dstt = snap_emb[st * 256 + tid];
    const float src0 = emb_cite[tid] + emb_ref[tid] + emb_target[tid];
    const float src1 = emb_cite[256 + tid] + emb_ref[256 + tid] + emb_target[256 + tid];

    // et table: head h == wave
    float p0 = leaky(src0 + dstt) * atv;
    float p1 = leaky(src1 + dstt) * atv;
#pragma unroll
    for (int off = 32; off; off >>= 1) {
        p0 += __shfl_xor(p0, off);
        p1 += __shfl_xor(p1, off);
    }
    if (lane == 0) {
        et_l[0][wave] = p0;
        et_l[1][wave] = p1;
    }
    __syncthreads();  // Tl + ic_l + et_l ready

    // logits: for each edge r, wave w reduces head w's 64 dims
    for (int r = 0; r < 32; r++) {
        const float v = __half2float(Tl[r * 256 + tid]) + f;
        float p = leaky(v) * av;
#pragma unroll
        for (int off = 32; off; off >>= 1) p += __shfl_xor(p, off);
        if (lane == 0) e_l[r][wave] = p + et_l[ic_l[r]][wave];
    }
    __syncthreads();

    // softmax over 32 edges per head: 128 threads in 32-lane subgroups
    if (tid < 128) {
        const int h = tid >> 5;
        const int r = tid & 31;
        const float e = e_l[r][h];
        float m = e;
#pragma unroll
        for (int off = 16; off; off >>= 1) m = fmaxf(m, __shfl_xor(m, off, 32));
        const float ex = __expf(e - m);
        float den = ex;
#pragma unroll
        for (int off = 16; off; off >>= 1) den += __shfl_xor(den, off, 32);
        a_l[r][h] = ex / den;
    }
    __syncthreads();

    // weighted sum: thread tid owns output dim tid (head = tid>>6)
    const int h = tid >> 6;
    float acc = 0.f;
#pragma unroll
    for (int r = 0; r < 32; r++) acc += a_l[r][h] * __half2float(Tl[r * 256 + tid]);
    sum_out[(long)s * 256 + tid] = __float2half(acc);
}

extern "C" void kernel_launch(void* const* d_in, const int* in_sizes, int n_in,
                              void* d_out, int out_size, void* d_ws, size_t ws_size,
                              hipStream_t stream) {
    const float* papers     = (const float*)d_in[0];
    const float* snapshots  = (const float*)d_in[1];
    const float* W_src      = (const float*)d_in[2];
    const float* b_src      = (const float*)d_in[3];
    const float* W_dst      = (const float*)d_in[4];
    const float* b_dst      = (const float*)d_in[5];
    const float* W_out      = (const float*)d_in[6];
    const float* b_out      = (const float*)d_in[7];
    const float* emb_cite   = (const float*)d_in[8];
    const float* emb_ref    = (const float*)d_in[9];
    const float* emb_target = (const float*)d_in[10];
    const float* snap_emb   = (const float*)d_in[11];
    const float* attn       = (const float*)d_in[12];
    const float* attn_t     = (const float*)d_in[13];
    const int* types        = (const int*)d_in[14];
    const int* is_cite      = (const int*)d_in[15];
    const int* sel          = (const int*)d_in[16];  // int32 on device (harness convention)

    char* ws = (char*)d_ws;
    float*  F    = (float*)ws;                        // 8192*256*4 = 8,388,608 B
    __half* SO   = (__half*)(ws + 8388608);           // 8192*256*2 = 4,194,304 B
    __half* feat = (__half*)(ws + 12582912);          // chunked edge features (f16)

    // snapshots per chunk, sized to available workspace (16,384 B per snapshot)
    size_t avail = ws_size > 12582912 ? ws_size - 12582912 : 0;
    long cs_l = (long)(avail / (PER * NDIM * sizeof(__half)));
    int chunkS = cs_l > NSNAP ? NSNAP : (int)cs_l;
    if (chunkS < 1) chunkS = 1;

    // 1) F = snapshots @ W_dst.T + b_dst (fp32)
    gemm_nt<float, float><<<dim3(64, 2), 256, 0, stream>>>(snapshots, W_dst, b_dst, F, NSNAP,
                                                           nullptr, 0);
    // 2+3) chunked: gather-GEMM edge features, then attention/softmax/aggregate
    for (int s0 = 0; s0 < NSNAP; s0 += chunkS) {
        const int cs = (s0 + chunkS <= NSNAP) ? chunkS : (NSNAP - s0);
        const int Mc = cs * PER;
        gemm_nt<float, __half><<<dim3((Mc + 127) / 128, 2), 256, 0, stream>>>(
            papers, W_src, b_src, feat, Mc, sel, s0 * PER);
        attn_kernel<<<cs, 256, 0, stream>>>(feat, F, emb_cite, emb_ref, emb_target, snap_emb,
                                            attn, attn_t, types, is_cite, sel, s0, SO);
    }
    // 4) out = SO @ W_out.T + b_out (fp32)
    gemm_nt<__half, float><<<dim3(64, 2), 256, 0, stream>>>(SO, W_out, b_out, (float*)d_out, NSNAP,
                                                            nullptr, 0);
}

// Round 3
// 414.310 us; speedup vs baseline: 1.6589x; 1.6589x over previous
//
#include <hip/hip_runtime.h>
#include <hip/hip_fp16.h>
#include <type_traits>

#define NSNAP 8192
#define PER 32
#define SLOPE 0.01f

using half8   = __attribute__((ext_vector_type(8))) _Float16;
using floatx4 = __attribute__((ext_vector_type(4))) float;

__device__ __forceinline__ float leaky(float x) { return x >= 0.f ? x : SLOPE * x; }

__device__ __forceinline__ unsigned pack2(float a, float b) {
    __half2 h = __floats2half2_rn(a, b);
    return *reinterpret_cast<unsigned*>(&h);
}

// W_src f32[256x256] -> f16 row-major (one-time)
__global__ __launch_bounds__(256) void pack_w(const float* __restrict__ W,
                                              _Float16* __restrict__ Wh) {
    const int i = blockIdx.x * 256 + threadIdx.x;  // 64 blocks -> 16384 tasks x4 elems
    const float4 v = *(const float4*)(W + (long)i * 4);
    *(uint2*)(Wh + (long)i * 4) = make_uint2(pack2(v.x, v.y), pack2(v.z, v.w));
}

// C[M,256] = A[M,256] @ W[256,256]^T + bias   (used for F and the final output)
template <typename AT, typename OT>
__global__ __launch_bounds__(256) void gemm_nt(const AT* __restrict__ A,
                                               const float* __restrict__ W,
                                               const float* __restrict__ bias,
                                               OT* __restrict__ Cout, int M) {
    constexpr int LDA = 40;
    __shared__ _Float16 Asl[128 * LDA];
    __shared__ _Float16 Wsl[128 * LDA];

    const int m0 = blockIdx.x * 128;
    const int n0 = blockIdx.y * 128;
    const int tid = threadIdx.x;
    const int lane = tid & 63;
    const int wave = tid >> 6;
    const int wm = (wave & 1) * 64;
    const int wn = (wave >> 1) * 64;
    const int l15 = lane & 15;
    const int quad = lane >> 4;

    floatx4 acc[4][4];
#pragma unroll
    for (int i = 0; i < 4; i++)
#pragma unroll
        for (int j = 0; j < 4; j++) acc[i][j] = (floatx4)0.f;

    for (int k0 = 0; k0 < 256; k0 += 32) {
        __syncthreads();
#pragma unroll
        for (int it = 0; it < 4; ++it) {
            const int idx = tid + it * 256;
            const int row = idx >> 3;
            const int c4 = idx & 7;
            long gm = (long)m0 + row;
            if (gm >= M) gm = M - 1;
            if constexpr (std::is_same_v<AT, float>) {
                const float4 v = *(const float4*)(A + gm * 256 + k0 + c4 * 4);
                *(uint2*)(&Asl[row * LDA + c4 * 4]) = make_uint2(pack2(v.x, v.y), pack2(v.z, v.w));
            } else {
                const uint2 v = *(const uint2*)(A + gm * 256 + k0 + c4 * 4);
                *(uint2*)(&Asl[row * LDA + c4 * 4]) = v;
            }
            const float4 w = *(const float4*)(W + (long)(n0 + row) * 256 + k0 + c4 * 4);
            *(uint2*)(&Wsl[row * LDA + c4 * 4]) = make_uint2(pack2(w.x, w.y), pack2(w.z, w.w));
        }
        __syncthreads();

        half8 af[4], bf[4];
#pragma unroll
        for (int i = 0; i < 4; i++)
            af[i] = *reinterpret_cast<const half8*>(&Asl[(wm + i * 16 + l15) * LDA + quad * 8]);
#pragma unroll
        for (int j = 0; j < 4; j++)
            bf[j] = *reinterpret_cast<const half8*>(&Wsl[(wn + j * 16 + l15) * LDA + quad * 8]);
#pragma unroll
        for (int i = 0; i < 4; i++)
#pragma unroll
            for (int j = 0; j < 4; j++)
                acc[i][j] = __builtin_amdgcn_mfma_f32_16x16x32_f16(af[i], bf[j], acc[i][j], 0, 0, 0);
    }

#pragma unroll
    for (int j = 0; j < 4; j++) {
        const int gcol = n0 + wn + j * 16 + l15;
        const float bv = bias[gcol];
#pragma unroll
        for (int i = 0; i < 4; i++) {
            const int rbase = m0 + wm + i * 16 + quad * 4;
#pragma unroll
            for (int r = 0; r < 4; r++) {
                const int grow = rbase + r;
                if (grow < M) {
                    const float v = acc[i][j][r] + bv;
                    if constexpr (std::is_same_v<OT, __half>)
                        Cout[(long)grow * 256 + gcol] = __float2half(v);
                    else
                        Cout[(long)grow * 256 + gcol] = v;
                }
            }
        }
    }
}

// Fused: gather-GEMM (feat = papers[sel] @ W_src.T + b_src) + per-head logits +
// segment softmax + weighted aggregate, all in-register. Block = 2 snapshots
// (64 edges) x 256 cols; wave w owns head w (cols 64w..64w+63).
__global__ __launch_bounds__(256, 2) void fused_attn(
    const float* __restrict__ papers, const _Float16* __restrict__ Wh,
    const float* __restrict__ b_src, const float* __restrict__ F,
    const float* __restrict__ emb_cite, const float* __restrict__ emb_ref,
    const float* __restrict__ emb_target, const float* __restrict__ snap_emb,
    const float* __restrict__ attn, const float* __restrict__ attn_t,
    const int* __restrict__ types, const int* __restrict__ is_cite,
    const int* __restrict__ sel, __half* __restrict__ SO) {
    constexpr int LDA = 40;  // halfs; 80 B rows keep 16B alignment, 2-way-max banks
    __shared__ _Float16 Asl[64 * LDA];
    __shared__ _Float16 Wsl[256 * LDA];
    __shared__ int ic_l[64];

    const int tid = threadIdx.x;
    const int lane = tid & 63;
    const int wave = tid >> 6;
    const int l15 = lane & 15;
    const int quad = lane >> 4;
    const int sbase = blockIdx.x * 2;
    const int ebase = blockIdx.x * 64;

    if (tid < 64) ic_l[tid] = is_cite[sel[ebase + tid]];

    // gather row: fixed per thread, hoisted out of the K-loop
    const int arow_idx = tid >> 2;  // 0..63
    const int ac8 = tid & 3;        // 8-float chunk within the 32-float K-slice
    const long arow = (long)sel[ebase + arow_idx];

    floatx4 acc[4][4];
#pragma unroll
    for (int i = 0; i < 4; i++)
#pragma unroll
        for (int j = 0; j < 4; j++) acc[i][j] = (floatx4)0.f;

    for (int k0 = 0; k0 < 256; k0 += 32) {
        __syncthreads();
        // A: 64 rows x 32 halfs; one uint4 LDS write per thread
        const float4 a0 = *(const float4*)(papers + arow * 256 + k0 + ac8 * 8);
        const float4 a1 = *(const float4*)(papers + arow * 256 + k0 + ac8 * 8 + 4);
        *(uint4*)(&Asl[arow_idx * LDA + ac8 * 8]) =
            make_uint4(pack2(a0.x, a0.y), pack2(a0.z, a0.w), pack2(a1.x, a1.y), pack2(a1.z, a1.w));
        // W: 256 rows x 32 halfs, pre-packed f16; 4 uint4 copies per thread
#pragma unroll
        for (int it = 0; it < 4; ++it) {
            const int task = tid + it * 256;
            const int n = task >> 2;
            const int c = task & 3;
            *(uint4*)(&Wsl[n * LDA + c * 8]) = *(const uint4*)(Wh + n * 256 + k0 + c * 8);
        }
        __syncthreads();

        half8 af[4], bf[4];
#pragma unroll
        for (int i = 0; i < 4; i++)
            af[i] = *reinterpret_cast<const half8*>(&Asl[(i * 16 + l15) * LDA + quad * 8]);
#pragma unroll
        for (int j = 0; j < 4; j++)
            bf[j] = *reinterpret_cast<const half8*>(&Wsl[(64 * wave + j * 16 + l15) * LDA + quad * 8]);
#pragma unroll
        for (int i = 0; i < 4; i++)
#pragma unroll
            for (int j = 0; j < 4; j++)
                acc[i][j] = __builtin_amdgcn_mfma_f32_16x16x32_f16(af[i], bf[j], acc[i][j], 0, 0, 0);
    }

    // ===== fused epilogue =====
    // acc[i][j][r] = feat[row = i*16 + quad*4 + r][col = 64*wave + j*16 + l15]
    float bsrc_j[4], attn_j[4], F0_j[4], F1_j[4];
#pragma unroll
    for (int j = 0; j < 4; j++) {
        const int col = 64 * wave + j * 16 + l15;
        bsrc_j[j] = b_src[col];
        attn_j[j] = attn[col];
        F0_j[j] = F[(long)sbase * 256 + col];
        F1_j[j] = F[(long)(sbase + 1) * 256 + col];
    }
#pragma unroll
    for (int i = 0; i < 4; i++)
#pragma unroll
        for (int j = 0; j < 4; j++)
#pragma unroll
            for (int r = 0; r < 4; r++) acc[i][j][r] += bsrc_j[j];

    // et[sn][ic] for this head: 64-dim reduce across the wave's lanes
    const int D = 64 * wave + lane;
    const float at_d = attn_t[D];
    const float src0 = emb_cite[D] + emb_ref[D] + emb_target[D];
    const float src1 = emb_cite[256 + D] + emb_ref[256 + D] + emb_target[256 + D];
    float et[2][2];
#pragma unroll
    for (int sn = 0; sn < 2; sn++) {
        const float dstt = snap_emb[types[sbase + sn] * 256 + D];
        float p0 = leaky(src0 + dstt) * at_d;
        float p1 = leaky(src1 + dstt) * at_d;
#pragma unroll
        for (int off = 32; off; off >>= 1) {
            p0 += __shfl_xor(p0, off);
            p1 += __shfl_xor(p1, off);
        }
        et[sn][0] = p0;
        et[sn][1] = p1;
    }

    // logits: reduce 64 head-dims = in-lane over j + shfl over the 16 l15 lanes
    float lg[4][4];
#pragma unroll
    for (int i = 0; i < 4; i++) {
        const int sn = i >> 1;
#pragma unroll
        for (int r = 0; r < 4; r++) {
            float p = 0.f;
#pragma unroll
            for (int j = 0; j < 4; j++)
                p += leaky(acc[i][j][r] + (sn == 0 ? F0_j[j] : F1_j[j])) * attn_j[j];
#pragma unroll
            for (int off = 1; off <= 8; off <<= 1) p += __shfl_xor(p, off);
            const int row = i * 16 + quad * 4 + r;
            lg[i][r] = p + et[sn][ic_l[row]];
        }
    }

    // segment softmax over 32 edges per snapshot: in-lane 8 + shfl across quads
    float aw[4][4];
#pragma unroll
    for (int sn = 0; sn < 2; sn++) {
        float m = -3.4e38f;
#pragma unroll
        for (int ii = 0; ii < 2; ii++)
#pragma unroll
            for (int r = 0; r < 4; r++) m = fmaxf(m, lg[sn * 2 + ii][r]);
        m = fmaxf(m, __shfl_xor(m, 16));
        m = fmaxf(m, __shfl_xor(m, 32));
        float den = 0.f;
#pragma unroll
        for (int ii = 0; ii < 2; ii++)
#pragma unroll
            for (int r = 0; r < 4; r++) {
                const float ex = __expf(lg[sn * 2 + ii][r] - m);
                aw[sn * 2 + ii][r] = ex;
                den += ex;
            }
        den += __shfl_xor(den, 16);
        den += __shfl_xor(den, 32);
        const float inv = 1.f / den;
#pragma unroll
        for (int ii = 0; ii < 2; ii++)
#pragma unroll
            for (int r = 0; r < 4; r++) aw[sn * 2 + ii][r] *= inv;
    }

    // weighted aggregate over each snapshot's 32 edges; write SO (f16)
#pragma unroll
    for (int sn = 0; sn < 2; sn++) {
#pragma unroll
        for (int j = 0; j < 4; j++) {
            float o = 0.f;
#pragma unroll
            for (int ii = 0; ii < 2; ii++)
#pragma unroll
                for (int r = 0; r < 4; r++) o += aw[sn * 2 + ii][r] * acc[sn * 2 + ii][j][r];
            o += __shfl_xor(o, 16);
            o += __shfl_xor(o, 32);
            if (quad == sn)
                SO[(long)(sbase + sn) * 256 + 64 * wave + j * 16 + l15] = __float2half(o);
        }
    }
}

extern "C" void kernel_launch(void* const* d_in, const int* in_sizes, int n_in,
                              void* d_out, int out_size, void* d_ws, size_t ws_size,
                              hipStream_t stream) {
    const float* papers     = (const float*)d_in[0];
    const float* snapshots  = (const float*)d_in[1];
    const float* W_src      = (const float*)d_in[2];
    const float* b_src      = (const float*)d_in[3];
    const float* W_dst      = (const float*)d_in[4];
    const float* b_dst      = (const float*)d_in[5];
    const float* W_out      = (const float*)d_in[6];
    const float* b_out      = (const float*)d_in[7];
    const float* emb_cite   = (const float*)d_in[8];
    const float* emb_ref    = (const float*)d_in[9];
    const float* emb_target = (const float*)d_in[10];
    const float* snap_emb   = (const float*)d_in[11];
    const float* attn       = (const float*)d_in[12];
    const float* attn_t     = (const float*)d_in[13];
    const int* types        = (const int*)d_in[14];
    const int* is_cite      = (const int*)d_in[15];
    const int* sel          = (const int*)d_in[16];  // int32 (harness convention)

    char* ws = (char*)d_ws;
    float*     F    = (float*)ws;                     // 8,388,608 B
    __half*    SO   = (__half*)(ws + 8388608);        // 4,194,304 B
    _Float16*  Wh   = (_Float16*)(ws + 12582912);     //   131,072 B

    // 1) pre-pack W_src to f16
    pack_w<<<64, 256, 0, stream>>>(W_src, Wh);
    // 2) F = snapshots @ W_dst.T + b_dst (fp32)
    gemm_nt<float, float><<<dim3(64, 2), 256, 0, stream>>>(snapshots, W_dst, b_dst, F, NSNAP);
    // 3) fused gather-GEMM + attention + softmax + aggregate -> SO
    fused_attn<<<NSNAP / 2, 256, 0, stream>>>(papers, Wh, b_src, F, emb_cite, emb_ref,
                                              emb_target, snap_emb, attn, attn_t, types,
                                              is_cite, sel, SO);
    // 4) out = SO @ W_out.T + b_out (fp32)
    gemm_nt<__half, float><<<dim3(64, 2), 256, 0, stream>>>(SO, W_out, b_out, (float*)d_out, NSNAP);
}

// Round 4
// 404.798 us; speedup vs baseline: 1.6979x; 1.0235x over previous
//
#include <hip/hip_runtime.h>
#include <hip/hip_fp16.h>
#include <type_traits>

#define NSNAP 8192
#define PER 32
#define SLOPE 0.01f

using half8   = __attribute__((ext_vector_type(8))) _Float16;
using floatx4 = __attribute__((ext_vector_type(4))) float;

__device__ __forceinline__ float leaky(float x) { return x >= 0.f ? x : SLOPE * x; }

__device__ __forceinline__ unsigned pack2(float a, float b) {
    __half2 h = __floats2half2_rn(a, b);
    return *reinterpret_cast<unsigned*>(&h);
}

// Pre-pack W_src f32[256][256] into f16 MFMA B-fragment order:
// Wh[(k0*16 + w*4 + j)*64 + lane] (half8) = W[n = w*64 + j*16 + (lane&15)]
//                                            [k = k0*32 + (lane>>4)*8 .. +8]
__global__ __launch_bounds__(256) void pack_w_frag(const float* __restrict__ W,
                                                   _Float16* __restrict__ Wh) {
    const int t = blockIdx.x * 256 + threadIdx.x;  // 128 blocks -> 32768 half8s
    const int lane = t & 63;
    const int wj = (t >> 6) & 15;
    const int k0 = t >> 10;
    const int n = (wj >> 2) * 64 + (wj & 3) * 16 + (lane & 15);
    const int k = k0 * 32 + (lane >> 4) * 8;
    const float4 v0 = *(const float4*)(W + (long)n * 256 + k);
    const float4 v1 = *(const float4*)(W + (long)n * 256 + k + 4);
    *(uint4*)(Wh + (long)t * 8) =
        make_uint4(pack2(v0.x, v0.y), pack2(v0.z, v0.w), pack2(v1.x, v1.y), pack2(v1.z, v1.w));
}

// C[M,256] = A[M,256] @ W[256,256]^T + bias   (used for F and the final output)
template <typename AT, typename OT>
__global__ __launch_bounds__(256) void gemm_nt(const AT* __restrict__ A,
                                               const float* __restrict__ W,
                                               const float* __restrict__ bias,
                                               OT* __restrict__ Cout, int M) {
    constexpr int LDA = 40;
    __shared__ _Float16 Asl[128 * LDA];
    __shared__ _Float16 Wsl[128 * LDA];

    const int m0 = blockIdx.x * 128;
    const int n0 = blockIdx.y * 128;
    const int tid = threadIdx.x;
    const int lane = tid & 63;
    const int wave = tid >> 6;
    const int wm = (wave & 1) * 64;
    const int wn = (wave >> 1) * 64;
    const int l15 = lane & 15;
    const int quad = lane >> 4;

    floatx4 acc[4][4];
#pragma unroll
    for (int i = 0; i < 4; i++)
#pragma unroll
        for (int j = 0; j < 4; j++) acc[i][j] = (floatx4)0.f;

    for (int k0 = 0; k0 < 256; k0 += 32) {
        __syncthreads();
#pragma unroll
        for (int it = 0; it < 4; ++it) {
            const int idx = tid + it * 256;
            const int row = idx >> 3;
            const int c4 = idx & 7;
            long gm = (long)m0 + row;
            if (gm >= M) gm = M - 1;
            if constexpr (std::is_same_v<AT, float>) {
                const float4 v = *(const float4*)(A + gm * 256 + k0 + c4 * 4);
                *(uint2*)(&Asl[row * LDA + c4 * 4]) = make_uint2(pack2(v.x, v.y), pack2(v.z, v.w));
            } else {
                const uint2 v = *(const uint2*)(A + gm * 256 + k0 + c4 * 4);
                *(uint2*)(&Asl[row * LDA + c4 * 4]) = v;
            }
            const float4 w = *(const float4*)(W + (long)(n0 + row) * 256 + k0 + c4 * 4);
            *(uint2*)(&Wsl[row * LDA + c4 * 4]) = make_uint2(pack2(w.x, w.y), pack2(w.z, w.w));
        }
        __syncthreads();

        half8 af[4], bf[4];
#pragma unroll
        for (int i = 0; i < 4; i++)
            af[i] = *reinterpret_cast<const half8*>(&Asl[(wm + i * 16 + l15) * LDA + quad * 8]);
#pragma unroll
        for (int j = 0; j < 4; j++)
            bf[j] = *reinterpret_cast<const half8*>(&Wsl[(wn + j * 16 + l15) * LDA + quad * 8]);
#pragma unroll
        for (int i = 0; i < 4; i++)
#pragma unroll
            for (int j = 0; j < 4; j++)
                acc[i][j] = __builtin_amdgcn_mfma_f32_16x16x32_f16(af[i], bf[j], acc[i][j], 0, 0, 0);
    }

#pragma unroll
    for (int j = 0; j < 4; j++) {
        const int gcol = n0 + wn + j * 16 + l15;
        const float bv = bias[gcol];
#pragma unroll
        for (int i = 0; i < 4; i++) {
            const int rbase = m0 + wm + i * 16 + quad * 4;
#pragma unroll
            for (int r = 0; r < 4; r++) {
                const int grow = rbase + r;
                if (grow < M) {
                    const float v = acc[i][j][r] + bv;
                    if constexpr (std::is_same_v<OT, __half>)
                        Cout[(long)grow * 256 + gcol] = __float2half(v);
                    else
                        Cout[(long)grow * 256 + gcol] = v;
                }
            }
        }
    }
}

// Fused gather-GEMM + attention. Block = 2 snapshots (64 edges); wave w = head w.
// A-tile (64x256) gathered+converted to LDS once (fragment-swizzled); W fragments
// loaded straight from L2-resident pre-packed Wh. Single barrier, barrier-free K-loop.
__global__ __launch_bounds__(256, 2) void fused_attn(
    const float* __restrict__ papers, const _Float16* __restrict__ Wh,
    const float* __restrict__ b_src, const float* __restrict__ F,
    const float* __restrict__ emb_cite, const float* __restrict__ emb_ref,
    const float* __restrict__ emb_target, const float* __restrict__ snap_emb,
    const float* __restrict__ attn, const float* __restrict__ attn_t,
    const int* __restrict__ types, const int* __restrict__ is_cite,
    const int* __restrict__ sel, __half* __restrict__ SO) {
    __shared__ _Float16 Asl[64 * 256];  // fragment-swizzled, 32 KB
    __shared__ int ic_l[64];

    const int tid = threadIdx.x;
    const int lane = tid & 63;
    const int wave = tid >> 6;
    const int l15 = lane & 15;
    const int quad = lane >> 4;
    const int sbase = blockIdx.x * 2;
    const int ebase = blockIdx.x * 64;

    if (tid < 64) ic_l[tid] = is_cite[sel[ebase + tid]];

    // ---- stage whole gathered A-tile: thread owns row r=tid>>2, 256B segment ----
    {
        const int r = tid >> 2;
        const int q0 = tid & 3;
        const long arow = (long)sel[ebase + r];
        const float* src = papers + arow * 256 + q0 * 64;
        const int i = r >> 4;
        const int rl = r & 15;
#pragma unroll
        for (int m = 0; m < 8; m++) {
            const float4 a0 = *(const float4*)(src + m * 8);
            const float4 a1 = *(const float4*)(src + m * 8 + 4);
            const int c8 = q0 * 8 + m;
            const int addr8 = (c8 >> 2) * 256 + i * 64 + (c8 & 3) * 16 + rl;
            *(uint4*)(&Asl[addr8 * 8]) = make_uint4(pack2(a0.x, a0.y), pack2(a0.z, a0.w),
                                                    pack2(a1.x, a1.y), pack2(a1.z, a1.w));
        }
    }
    __syncthreads();  // the only barrier

    floatx4 acc[4][4];
#pragma unroll
    for (int i = 0; i < 4; i++)
#pragma unroll
        for (int j = 0; j < 4; j++) acc[i][j] = (floatx4)0.f;

    // ---- barrier-free K-loop: LDS A-frags + global (L2) W-frags + MFMA ----
    for (int k0 = 0; k0 < 8; k0++) {
        half8 af[4], bf[4];
#pragma unroll
        for (int i = 0; i < 4; i++)
            af[i] = *reinterpret_cast<const half8*>(&Asl[(k0 * 256 + i * 64 + lane) * 8]);
#pragma unroll
        for (int j = 0; j < 4; j++)
            bf[j] = *reinterpret_cast<const half8*>(Wh + ((k0 * 16 + wave * 4 + j) * 64 + lane) * 8);
#pragma unroll
        for (int i = 0; i < 4; i++)
#pragma unroll
            for (int j = 0; j < 4; j++)
                acc[i][j] = __builtin_amdgcn_mfma_f32_16x16x32_f16(af[i], bf[j], acc[i][j], 0, 0, 0);
    }

    // ===== fused epilogue =====
    // acc[i][j][r] = feat[row = i*16 + quad*4 + r][col = 64*wave + j*16 + l15]
    float bsrc_j[4], attn_j[4], F0_j[4], F1_j[4];
#pragma unroll
    for (int j = 0; j < 4; j++) {
        const int col = 64 * wave + j * 16 + l15;
        bsrc_j[j] = b_src[col];
        attn_j[j] = attn[col];
        F0_j[j] = F[(long)sbase * 256 + col];
        F1_j[j] = F[(long)(sbase + 1) * 256 + col];
    }
#pragma unroll
    for (int i = 0; i < 4; i++)
#pragma unroll
        for (int j = 0; j < 4; j++)
#pragma unroll
            for (int r = 0; r < 4; r++) acc[i][j][r] += bsrc_j[j];

    // et[sn][ic] for this head: 64-dim reduce across the wave
    const int D = 64 * wave + lane;
    const float at_d = attn_t[D];
    const float src0 = emb_cite[D] + emb_ref[D] + emb_target[D];
    const float src1 = emb_cite[256 + D] + emb_ref[256 + D] + emb_target[256 + D];
    float et[2][2];
#pragma unroll
    for (int sn = 0; sn < 2; sn++) {
        const float dstt = snap_emb[types[sbase + sn] * 256 + D];
        float p0 = leaky(src0 + dstt) * at_d;
        float p1 = leaky(src1 + dstt) * at_d;
#pragma unroll
        for (int off = 32; off; off >>= 1) {
            p0 += __shfl_xor(p0, off);
            p1 += __shfl_xor(p1, off);
        }
        et[sn][0] = p0;
        et[sn][1] = p1;
    }

    // logits: in-lane over j + shfl over the 16 l15 lanes
    float lg[4][4];
#pragma unroll
    for (int i = 0; i < 4; i++) {
        const int sn = i >> 1;
#pragma unroll
        for (int r = 0; r < 4; r++) {
            float p = 0.f;
#pragma unroll
            for (int j = 0; j < 4; j++)
                p += leaky(acc[i][j][r] + (sn == 0 ? F0_j[j] : F1_j[j])) * attn_j[j];
#pragma unroll
            for (int off = 1; off <= 8; off <<= 1) p += __shfl_xor(p, off);
            const int row = i * 16 + quad * 4 + r;
            lg[i][r] = p + et[sn][ic_l[row]];
        }
    }

    // segment softmax over 32 edges per snapshot
    float aw[4][4];
#pragma unroll
    for (int sn = 0; sn < 2; sn++) {
        float m = -3.4e38f;
#pragma unroll
        for (int ii = 0; ii < 2; ii++)
#pragma unroll
            for (int r = 0; r < 4; r++) m = fmaxf(m, lg[sn * 2 + ii][r]);
        m = fmaxf(m, __shfl_xor(m, 16));
        m = fmaxf(m, __shfl_xor(m, 32));
        float den = 0.f;
#pragma unroll
        for (int ii = 0; ii < 2; ii++)
#pragma unroll
            for (int r = 0; r < 4; r++) {
                const float ex = __expf(lg[sn * 2 + ii][r] - m);
                aw[sn * 2 + ii][r] = ex;
                den += ex;
            }
        den += __shfl_xor(den, 16);
        den += __shfl_xor(den, 32);
        const float inv = 1.f / den;
#pragma unroll
        for (int ii = 0; ii < 2; ii++)
#pragma unroll
            for (int r = 0; r < 4; r++) aw[sn * 2 + ii][r] *= inv;
    }

    // weighted aggregate; write SO (f16)
#pragma unroll
    for (int sn = 0; sn < 2; sn++) {
#pragma unroll
        for (int j = 0; j < 4; j++) {
            float o = 0.f;
#pragma unroll
            for (int ii = 0; ii < 2; ii++)
#pragma unroll
                for (int r = 0; r < 4; r++) o += aw[sn * 2 + ii][r] * acc[sn * 2 + ii][j][r];
            o += __shfl_xor(o, 16);
            o += __shfl_xor(o, 32);
            if (quad == sn)
                SO[(long)(sbase + sn) * 256 + 64 * wave + j * 16 + l15] = __float2half(o);
        }
    }
}

extern "C" void kernel_launch(void* const* d_in, const int* in_sizes, int n_in,
                              void* d_out, int out_size, void* d_ws, size_t ws_size,
                              hipStream_t stream) {
    const float* papers     = (const float*)d_in[0];
    const float* snapshots  = (const float*)d_in[1];
    const float* W_src      = (const float*)d_in[2];
    const float* b_src      = (const float*)d_in[3];
    const float* W_dst      = (const float*)d_in[4];
    const float* b_dst      = (const float*)d_in[5];
    const float* W_out      = (const float*)d_in[6];
    const float* b_out      = (const float*)d_in[7];
    const float* emb_cite   = (const float*)d_in[8];
    const float* emb_ref    = (const float*)d_in[9];
    const float* emb_target = (const float*)d_in[10];
    const float* snap_emb   = (const float*)d_in[11];
    const float* attn       = (const float*)d_in[12];
    const float* attn_t     = (const float*)d_in[13];
    const int* types        = (const int*)d_in[14];
    const int* is_cite      = (const int*)d_in[15];
    const int* sel          = (const int*)d_in[16];  // int32 (harness convention)

    char* ws = (char*)d_ws;
    float*     F    = (float*)ws;                     // 8,388,608 B
    __half*    SO   = (__half*)(ws + 8388608);        // 4,194,304 B
    _Float16*  Wh   = (_Float16*)(ws + 12582912);     //   131,072 B (fragment order)

    // 1) pre-pack W_src into MFMA fragment order
    pack_w_frag<<<128, 256, 0, stream>>>(W_src, Wh);
    // 2) F = snapshots @ W_dst.T + b_dst (fp32)
    gemm_nt<float, float><<<dim3(64, 2), 256, 0, stream>>>(snapshots, W_dst, b_dst, F, NSNAP);
    // 3) fused gather-GEMM + attention + softmax + aggregate -> SO
    fused_attn<<<NSNAP / 2, 256, 0, stream>>>(papers, Wh, b_src, F, emb_cite, emb_ref,
                                              emb_target, snap_emb, attn, attn_t, types,
                                              is_cite, sel, SO);
    // 4) out = SO @ W_out.T + b_out (fp32)
    gemm_nt<__half, float><<<dim3(64, 2), 256, 0, stream>>>(SO, W_out, b_out, (float*)d_out, NSNAP);
}